// Round 2
// baseline (58.296 us; speedup 1.0000x reference)
//
#include <hip/hip_runtime.h>

#define TT 256
#define BB 256
#define DD 128
// out: outs[TT][BB][128] then hx[BB][128] then cx[BB][128]

__device__ __forceinline__ float frcp(float x) { return __builtin_amdgcn_rcpf(x); }
__device__ __forceinline__ float fastcos(float z) {
    float r = z * 0.15915494309189535f;      // radians -> revolutions
    r = __builtin_amdgcn_fractf(r);          // exact periodic reduction
    return __builtin_amdgcn_cosf(r);         // v_cos_f32 (revolutions)
}
#define C_SIG  (-1.4426950408889634f)        // -log2(e):  sigmoid(v) = rcp(1+exp2(C_SIG*v))
#define C_TANH (-2.8853900817779268f)        // -2log2(e): tanh(v) = 2*rcp(1+exp2(C_TANH*v))-1
#define C_TC   ( 2.8853900817779268f)        //  2log2(e): tanh(c) = 1-2*rcp(1+exp2(C_TC*c))

// Kernel 1: A[t*BB + b] = {a_f, a_i, a_u, a_o},  a_g = x[t,b,:] . Wg[0,0:128] + bg[0] + pg[0]
__global__ __launch_bounds__(256) void k_angles(
    const float* __restrict__ x,
    const float* __restrict__ Wf, const float* __restrict__ bf, const float* __restrict__ pf,
    const float* __restrict__ Wi, const float* __restrict__ bi, const float* __restrict__ pi,
    const float* __restrict__ Wu, const float* __restrict__ bu, const float* __restrict__ pu,
    const float* __restrict__ Wo, const float* __restrict__ bo, const float* __restrict__ po,
    float4* __restrict__ A)
{
    __shared__ float4 w4[4][32];             // row 0, cols 0..127 of each W
    float* w = reinterpret_cast<float*>(w4);
    int tid = threadIdx.x;
    for (int k = tid; k < 512; k += 256) {
        int g = k >> 7, j = k & 127;
        const float* W = (g == 0) ? Wf : (g == 1) ? Wi : (g == 2) ? Wu : Wo;
        w[g * 128 + j] = W[j];
    }
    __syncthreads();

    int r = blockIdx.x * 256 + tid;          // r = t*BB + b
    const float4* xr = reinterpret_cast<const float4*>(x + (size_t)r * DD);

    float af = bf[0] + pf[0];
    float ai = bi[0] + pi[0];
    float au = bu[0] + pu[0];
    float ao = bo[0] + po[0];
    #pragma unroll
    for (int k = 0; k < 32; ++k) {
        float4 v  = xr[k];
        float4 f4 = w4[0][k], i4 = w4[1][k], u4 = w4[2][k], o4 = w4[3][k];
        af = fmaf(v.x, f4.x, fmaf(v.y, f4.y, fmaf(v.z, f4.z, fmaf(v.w, f4.w, af))));
        ai = fmaf(v.x, i4.x, fmaf(v.y, i4.y, fmaf(v.z, i4.z, fmaf(v.w, i4.w, ai))));
        au = fmaf(v.x, u4.x, fmaf(v.y, u4.y, fmaf(v.z, u4.z, fmaf(v.w, u4.w, au))));
        ao = fmaf(v.x, o4.x, fmaf(v.y, o4.y, fmaf(v.z, o4.z, fmaf(v.w, o4.w, ao))));
    }
    A[r] = make_float4(af, ai, au, ao);      // coalesced [t][b] store
}

// Kernel 2: lane-per-sample serial recurrence. 4 blocks x 64 lanes = 256 samples.
// Writes compact h into A[t*BB+b].x (angle already consumed); final c into A[255*BB+b].y.
__global__ __launch_bounds__(64) void k_recur(
    float4* __restrict__ A,
    const float* __restrict__ Wf, const float* __restrict__ Wi,
    const float* __restrict__ Wu, const float* __restrict__ Wo)
{
    int bg = blockIdx.x * 64 + threadIdx.x;  // this lane's sample

    // S_g = sum Wg[0, 128:256]  (h is constant over hidden dim -> feedback is scalar)
    float Sf = 0.f, Si = 0.f, Su = 0.f, So = 0.f;
    {
        const float4* F4 = reinterpret_cast<const float4*>(Wf + 128);
        const float4* I4 = reinterpret_cast<const float4*>(Wi + 128);
        const float4* U4 = reinterpret_cast<const float4*>(Wu + 128);
        const float4* O4 = reinterpret_cast<const float4*>(Wo + 128);
        #pragma unroll
        for (int k = 0; k < 32; ++k) {
            float4 a = F4[k], b = I4[k], c = U4[k], d = O4[k];
            Sf += (a.x + a.y) + (a.z + a.w);
            Si += (b.x + b.y) + (b.z + b.w);
            Su += (c.x + c.y) + (c.z + c.w);
            So += (d.x + d.y) + (d.z + d.w);
        }
    }

    float4* Ab = A + bg;                     // column base; element t at Ab[t*BB]
    float c = 0.f, h = 0.f;

    // prefetch depth 8, named registers (runtime-indexed arrays would spill to scratch)
    float4 p0 = Ab[0*BB], p1 = Ab[1*BB], p2 = Ab[2*BB], p3 = Ab[3*BB];
    float4 p4 = Ab[4*BB], p5 = Ab[5*BB], p6 = Ab[6*BB], p7 = Ab[7*BB];

#define STEP(P, TIDX)                                                        \
    {                                                                        \
        float zf = fmaf(h, Sf, P.x), zi = fmaf(h, Si, P.y);                  \
        float zu = fmaf(h, Su, P.z), zo = fmaf(h, So, P.w);                  \
        float vf = fastcos(zf), vi = fastcos(zi);                            \
        float vu = fastcos(zu), vo = fastcos(zo);                            \
        float ef = __builtin_amdgcn_exp2f(vf * C_SIG);                       \
        float ei = __builtin_amdgcn_exp2f(vi * C_SIG);                       \
        float eu = __builtin_amdgcn_exp2f(vu * C_TANH);                      \
        float eo = __builtin_amdgcn_exp2f(vo * C_SIG);                       \
        float fg = frcp(1.f + ef), ig = frcp(1.f + ei), og = frcp(1.f + eo); \
        float ug = fmaf(2.f, frcp(1.f + eu), -1.f);                          \
        c = fmaf(fg, c, ig * ug);                                            \
        float e2 = __builtin_amdgcn_exp2f(c * C_TC);                         \
        float th = fmaf(-2.f, frcp(1.f + e2), 1.f);                          \
        h = og * th;                                                         \
        reinterpret_cast<float*>(Ab + (TIDX) * BB)[0] = h;                   \
    }

    for (int t = 0; t < TT; t += 8) {
        int tn = t + 8;
        STEP(p0, t + 0); p0 = Ab[(size_t)min(tn + 0, TT - 1) * BB];
        STEP(p1, t + 1); p1 = Ab[(size_t)min(tn + 1, TT - 1) * BB];
        STEP(p2, t + 2); p2 = Ab[(size_t)min(tn + 2, TT - 1) * BB];
        STEP(p3, t + 3); p3 = Ab[(size_t)min(tn + 3, TT - 1) * BB];
        STEP(p4, t + 4); p4 = Ab[(size_t)min(tn + 4, TT - 1) * BB];
        STEP(p5, t + 5); p5 = Ab[(size_t)min(tn + 5, TT - 1) * BB];
        STEP(p6, t + 6); p6 = Ab[(size_t)min(tn + 6, TT - 1) * BB];
        STEP(p7, t + 7); p7 = Ab[(size_t)min(tn + 7, TT - 1) * BB];
    }
#undef STEP
    reinterpret_cast<float*>(Ab + (TT - 1) * BB)[1] = c;   // final c -> A[255][b].y
}

// Kernel 3: broadcast expand. outs[t][b][j] = A[t*BB+b].x; hx = A[255][b].x; cx = A[255][b].y
__global__ __launch_bounds__(256) void k_expand(
    const float4* __restrict__ A, float4* __restrict__ out)
{
    unsigned r = blockIdx.x * 256 + threadIdx.x;     // one float4 of output
    const unsigned OUTS4 = (unsigned)TT * BB * 128 / 4;   // 2,097,152
    const unsigned HX4   = (unsigned)BB * 128 / 4;        // 8,192
    float v;
    if (r < OUTS4) {
        v = A[r >> 5].x;                              // 32 float4 per (t,b)
    } else {
        unsigned q = r - OUTS4;
        unsigned b = (q & (HX4 - 1)) >> 5;
        float4 a = A[(TT - 1) * BB + b];
        v = (q < HX4) ? a.x : a.y;
    }
    out[r] = make_float4(v, v, v, v);
}

extern "C" void kernel_launch(void* const* d_in, const int* in_sizes, int n_in,
                              void* d_out, int out_size, void* d_ws, size_t ws_size,
                              hipStream_t stream) {
    const float* x = (const float*)d_in[0];
    const float *Wf, *bf, *pf, *Wi, *bi, *pi, *Wu, *bu, *pu, *Wo, *bo, *po;
    if (n_in >= 13 && in_sizes[3] == 8 && in_sizes[4] == 2048) {
        // setup_inputs dict order: (Wf,bf,pf),(Wi,bi,pi),(Wu,bu,pu),(Wo,bo,po)
        Wf = (const float*)d_in[1];  bf = (const float*)d_in[2];  pf = (const float*)d_in[3];
        Wi = (const float*)d_in[4];  bi = (const float*)d_in[5];  pi = (const float*)d_in[6];
        Wu = (const float*)d_in[7];  bu = (const float*)d_in[8];  pu = (const float*)d_in[9];
        Wo = (const float*)d_in[10]; bo = (const float*)d_in[11]; po = (const float*)d_in[12];
    } else {
        // reference signature order: Wf,bf,Wi,bi,Wu,bu,Wo,bo,pf,pi,pu,po
        Wf = (const float*)d_in[1];  bf = (const float*)d_in[2];
        Wi = (const float*)d_in[3];  bi = (const float*)d_in[4];
        Wu = (const float*)d_in[5];  bu = (const float*)d_in[6];
        Wo = (const float*)d_in[7];  bo = (const float*)d_in[8];
        pf = (const float*)d_in[9];  pi = (const float*)d_in[10];
        pu = (const float*)d_in[11]; po = (const float*)d_in[12];
    }
    float4* A = (float4*)d_ws;                 // 65536 * 16B = 1 MiB scratch

    k_angles<<<dim3(256), dim3(256), 0, stream>>>(
        x, Wf, bf, pf, Wi, bi, pi, Wu, bu, pu, Wo, bo, po, A);
    k_recur<<<dim3(4), dim3(64), 0, stream>>>(A, Wf, Wi, Wu, Wo);
    k_expand<<<dim3((TT * BB * 128 / 4 + 2 * BB * 128 / 4) / 256), dim3(256), 0, stream>>>(
        A, (float4*)d_out);
}